// Round 1
// baseline (167.734 us; speedup 1.0000x reference)
//
#include <hip/hip_runtime.h>
#include <math.h>

#define N_NODES 50000
#define M_NEIGH 16
#define HID     64
#define BATCH   4

typedef float fvec4 __attribute__((ext_vector_type(4)));

// R12: single fused fp32 kernel (improved R4 fallback). Rationale:
//  - The two-dispatch int8 slab pipeline measured 121.6 us while BOTH its
//    kernels individually ran < 42.2 us (absent from rocprof top-5): the
//    convert round-trip + second dependent launch + cold-L2 restart never
//    paid for the cheaper gather. R4's single fp32 kernel benched 68 us.
//  - vs R4: full H per 8-lane group (index read 4x not 8x, 32 outstanding
//    16 B loads/lane instead of 16), and each store instruction writes
//    aligned full 128 B sectors (8 consecutive rows x half-row) -- no
//    partial-sector amplification (the R10 failure mode).
//  - Pad rows (idx == N_NODES) occur with P ~ 3e-5 per slot; hot loop has
//    no selects -- a node with any pad neighbor takes the branchless
//    slow path (group-uniform branch, ~0.03% of lanes).
//  - x (51.2 MB total) is L3-resident; gather demand 819 MB is served by
//    Infinity Cache. blockIdx&3 = batch pins each batch's 12.8 MB panel
//    to an XCD pair (blocks round-robin XCDs by blockIdx%8) for partial
//    L2 service on top of L3.
//  - absmax: exact fp32 -> 0.

__global__ __launch_bounds__(256, 4) void pool_max_f32(
    const fvec4* __restrict__ x,       // [B, N, 16] fvec4
    const int*   __restrict__ index,   // [N, 16] int32
    fvec4*       __restrict__ out)     // [B, N, 16] fvec4
{
    const int batch = blockIdx.x & 3;          // batch -> XCDs {b, b+4}
    const int group = blockIdx.x >> 2;
    const int wave  = threadIdx.x >> 6;
    const int lane  = threadIdx.x & 63;
    const int q8    = lane & 7;                // 32 B chunk owner within row
    const int li    = lane >> 3;               // node within wave (0..7)
    const int n     = group * 32 + wave * 8 + li;
    if (n >= N_NODES) return;

    const fvec4* xb = x + (size_t)batch * ((size_t)N_NODES * (HID / 4));

    // 16 neighbor indices for this node (8 lanes of the group load the same
    // row -> 16 B broadcast segments, dedup'd by the TA).
    const int4* ip = (const int4*)(index + (size_t)n * M_NEIGH);
    int idx[M_NEIGH];
#pragma unroll
    for (int mm = 0; mm < 4; ++mm) {
        const int4 r = ip[mm];
        idx[mm * 4 + 0] = r.x; idx[mm * 4 + 1] = r.y;
        idx[mm * 4 + 2] = r.z; idx[mm * 4 + 3] = r.w;
    }

    bool haspad = false;
#pragma unroll
    for (int m = 0; m < M_NEIGH; ++m) haspad |= (idx[m] >= N_NODES);

    fvec4 a0 = (fvec4){-INFINITY, -INFINITY, -INFINITY, -INFINITY};
    fvec4 a1 = (fvec4){-INFINITY, -INFINITY, -INFINITY, -INFINITY};

    if (!haspad) {
        // Hot path (99.97% of nodes): no pad selects at all.
        // Per m: two fvec4 loads -> bytes [q8*16, +16) and [128+q8*16, +16)
        // of the 256 B row; per load instr the 8 groups hit 8 random rows,
        // 128 B contiguous each.
#pragma unroll
        for (int m = 0; m < M_NEIGH; ++m) {
            const size_t ro = (size_t)idx[m] * (HID / 4);
            const fvec4 v0 = xb[ro + q8];
            const fvec4 v1 = xb[ro + 8 + q8];
            a0.x = fmaxf(a0.x, v0.x); a0.y = fmaxf(a0.y, v0.y);
            a0.z = fmaxf(a0.z, v0.z); a0.w = fmaxf(a0.w, v0.w);
            a1.x = fmaxf(a1.x, v1.x); a1.y = fmaxf(a1.y, v1.y);
            a1.z = fmaxf(a1.z, v1.z); a1.w = fmaxf(a1.w, v1.w);
        }
    } else {
        // Rare path: branchless pad masking (pad row contributes 0.0f,
        // matching the reference's zero padding row).
#pragma unroll
        for (int m = 0; m < M_NEIGH; ++m) {
            const int r  = idx[m];
            const int rc = r < N_NODES ? r : 0;
            const size_t ro = (size_t)rc * (HID / 4);
            fvec4 v0 = xb[ro + q8];
            fvec4 v1 = xb[ro + 8 + q8];
            if (r >= N_NODES) {
                v0 = (fvec4){0.f, 0.f, 0.f, 0.f};
                v1 = (fvec4){0.f, 0.f, 0.f, 0.f};
            }
            a0.x = fmaxf(a0.x, v0.x); a0.y = fmaxf(a0.y, v0.y);
            a0.z = fmaxf(a0.z, v0.z); a0.w = fmaxf(a0.w, v0.w);
            a1.x = fmaxf(a1.x, v1.x); a1.y = fmaxf(a1.y, v1.y);
            a1.z = fmaxf(a1.z, v1.z); a1.w = fmaxf(a1.w, v1.w);
        }
    }

    // Lane q8 owns floats [4*q8, 4*q8+4) and [32+4*q8, +4) of the out row.
    // Store instr 0: 8 consecutive rows' first 128 B halves (aligned full
    // sectors); store instr 1: second halves. No partial-sector writes.
    fvec4* o = &out[((size_t)batch * N_NODES + n) * (HID / 4)];
    __builtin_nontemporal_store(a0, o + q8);
    __builtin_nontemporal_store(a1, o + 8 + q8);
}

extern "C" void kernel_launch(void* const* d_in, const int* in_sizes, int n_in,
                              void* d_out, int out_size, void* d_ws, size_t ws_size,
                              hipStream_t stream) {
    const fvec4* x   = (const fvec4*)d_in[0];
    const int*   idx = (const int*)d_in[1];
    fvec4*       out = (fvec4*)d_out;

    // 32 nodes per block (4 waves x 8 nodes), 4 batch partitions.
    const int groups = (N_NODES + 31) / 32;    // 1563
    pool_max_f32<<<groups * 4, 256, 0, stream>>>(x, idx, out);
}